// Round 11
// baseline (64.604 us; speedup 1.0000x reference)
//
#include <hip/hip_runtime.h>
#include <hip/hip_bf16.h>

#define EDIM 128

typedef __attribute__((ext_vector_type(4))) float f32x4;
typedef __attribute__((ext_vector_type(2))) float f32x2;
typedef __attribute__((ext_vector_type(8))) short bf16x8;

// fp4 e2m1 scales. emb table: x -> fp4(x * EMB_INV), decode * (2/3).
// h1 table:  x -> fp4(x * H1_INV),  decode * (1/6).
#define EMB_INV 1.5f
#define EMB_S_OVER16 0.04166667f   // (2/3)/16  (fold hop-1 mean into dequant)
#define H1_INV 6.0f
#define H1_S_OVER16 0.010416667f   // (1/6)/16  (fold hop-2 mean into dequant)

// ---- helpers ---------------------------------------------------------------
__device__ __forceinline__ unsigned pack_bf16(float lo, float hi) {
  __hip_bfloat16 l = __float2bfloat16(lo);
  __hip_bfloat16 h = __float2bfloat16(hi);
  unsigned short lu = *reinterpret_cast<unsigned short*>(&l);
  unsigned short hu = *reinterpret_cast<unsigned short*>(&h);
  return (unsigned)lu | ((unsigned)hu << 16);
}

// encode one float -> fp4 e2m1 nibble (round-to-nearest on the e2m1 grid)
__device__ __forceinline__ unsigned enc_fp4(float x, float inv) {
  unsigned s = (__float_as_uint(x) >> 31) << 3;
  float m = fabsf(x) * inv;
  unsigned idx = (unsigned)(m > 0.25f) + (m > 0.75f) + (m > 1.25f) + (m > 1.75f)
               + (m > 2.5f) + (m > 3.5f) + (m > 5.0f);
  return idx | s;
}

// pack 8 floats (fp32) -> 8 fp4 nibbles in one u32
__device__ __forceinline__ unsigned enc_fp4x8(const float* a, float pre, float inv) {
  unsigned o = 0;
#pragma unroll
  for (int j = 0; j < 8; ++j) o |= enc_fp4(a[j] * pre, inv) << (4 * j);
  return o;
}

// decode 8 fp4 nibbles (u32) -> 8 floats in fp4-grid units, TRUE element order.
// nibble j = element j. Route: nibble -> fp8 e4m3 byte via v_perm LUT
// (fp4 values {0,.5,1,1.5,2,3,4,6} are exact in e4m3), then cvt_pk_f32_fp8.
__device__ __forceinline__ void dec_fp4x8(unsigned u, float* a) {
  const unsigned LUT_LO = 0x3C383000u;
  const unsigned LUT_HI = 0x4C484440u;
  unsigned mE = u & 0x07070707u;
  unsigned mO = (u >> 4) & 0x07070707u;
  unsigned sE = (u & 0x08080808u) << 4;
  unsigned sO = u & 0x80808080u;
  unsigned E = __builtin_amdgcn_perm(LUT_HI, LUT_LO, mE) | sE;  // e0,e2,e4,e6
  unsigned O = __builtin_amdgcn_perm(LUT_HI, LUT_LO, mO) | sO;  // e1,e3,e5,e7
  f32x2 p;
  p = __builtin_amdgcn_cvt_pk_f32_fp8(E, false); a[0] = p.x; a[2] = p.y;
  p = __builtin_amdgcn_cvt_pk_f32_fp8(E, true);  a[4] = p.x; a[6] = p.y;
  p = __builtin_amdgcn_cvt_pk_f32_fp8(O, false); a[1] = p.x; a[3] = p.y;
  p = __builtin_amdgcn_cvt_pk_f32_fp8(O, true);  a[5] = p.x; a[7] = p.y;
}

// ---------------------------------------------------------------------------
// K0: emb fp32 -> fp4 table in 2-way COLUMN-SLICED layout [2][N][8 u32]
//     (slice s = columns [64s, 64s+64); sub-table = 3.2 MB, fits XCD L2),
//     W fp32 -> bf16 (row-major).
// ---------------------------------------------------------------------------
__global__ __launch_bounds__(256) void convert_kernel(
    const float* __restrict__ emb, unsigned* __restrict__ emb4, int nNodes,
    const float* __restrict__ W, unsigned short* __restrict__ Wb, int n8_w) {
  int n8_emb = nNodes * 16;
  int total = n8_emb + n8_w;
  for (int i = blockIdx.x * 256 + threadIdx.x; i < total; i += gridDim.x * 256) {
    if (i < n8_emb) {
      int n = i >> 4;       // node
      int j = i & 15;       // 8-float group within row
      const float4* s4 = reinterpret_cast<const float4*>(emb) + (size_t)i * 2;
      float4 a = s4[0], b = s4[1];
      unsigned u = enc_fp4(a.x, EMB_INV) | (enc_fp4(a.y, EMB_INV) << 4) |
                   (enc_fp4(a.z, EMB_INV) << 8) | (enc_fp4(a.w, EMB_INV) << 12) |
                   (enc_fp4(b.x, EMB_INV) << 16) | (enc_fp4(b.y, EMB_INV) << 20) |
                   (enc_fp4(b.z, EMB_INV) << 24) | (enc_fp4(b.w, EMB_INV) << 28);
      int s = j >> 3;       // slice (0/1)
      int w = j & 7;        // u32 within slice
      emb4[((size_t)s * nNodes + n) * 8 + w] = u;
    } else {
      int j = i - n8_emb;
      const float4* s4 = reinterpret_cast<const float4*>(W) + (size_t)j * 2;
      float4 a = s4[0], b = s4[1];
      uint4 o;
      o.x = pack_bf16(a.x, a.y);
      o.y = pack_bf16(a.z, a.w);
      o.z = pack_bf16(b.x, b.y);
      o.w = pack_bf16(b.z, b.w);
      *(reinterpret_cast<uint4*>(Wb) + j) = o;
    }
  }
}

// ---------------------------------------------------------------------------
// K1: h1_fp4[n] = mean over 16 neighbors of emb_fp4[nbr], 2-way column-sliced.
// GRID = 2048 blocks exactly (all co-resident on 256 CUs) so the round-robin
// bid->XCD mapping HOLDS for the kernel's whole life (r8 evidence: FETCH
// 18.9 MB at 1564 blocks; r10 counterexample: 6250 blocks -> pinning drifts,
// capacity misses return). slice = bid&1 -> slice s owns XCD parity s; its
// 3.2 MB sub-table is L2-resident. Blocks grid-stride over nodes.
// 8 lanes per (node, slice): lane owns u32 (tid&7) of the 32B slice row ->
// one coalesced 32B request per neighbor row-slice; acc[8], low VGPR.
// ---------------------------------------------------------------------------
__global__ __launch_bounds__(256) void hop1_kernel(
    const int* __restrict__ nbr, const unsigned* __restrict__ emb4,
    unsigned* __restrict__ dst4, int nNodes) {
  int slice = blockIdx.x & 1;
  int l8 = threadIdx.x & 7;
  const unsigned* sub = emb4 + (size_t)slice * nNodes * 8 + l8;
  int stride = (gridDim.x >> 1) * 32;  // nodes covered per sweep by one slice

  for (int node = (blockIdx.x >> 1) * 32 + (threadIdx.x >> 3); node < nNodes;
       node += stride) {
    const int4* nb4 = reinterpret_cast<const int4*>(nbr) + (size_t)node * 4;
    int4 a = nb4[0], b = nb4[1], c = nb4[2], d = nb4[3];
    int idx[16] = {a.x, a.y, a.z, a.w, b.x, b.y, b.z, b.w,
                   c.x, c.y, c.z, c.w, d.x, d.y, d.z, d.w};

    float acc[8] = {0.f, 0.f, 0.f, 0.f, 0.f, 0.f, 0.f, 0.f};
#pragma unroll
    for (int m = 0; m < 16; ++m) {
      unsigned u = sub[(size_t)idx[m] * 8];
      float t[8];
      dec_fp4x8(u, t);
#pragma unroll
      for (int j = 0; j < 8; ++j) acc[j] += t[j];
    }
    // h1 row layout [N][16 u32]; this thread owns u32 (slice*8 + l8)
    dst4[(size_t)node * 16 + slice * 8 + l8] =
        enc_fp4x8(acc, EMB_S_OVER16, H1_INV);
  }
}

// ---------------------------------------------------------------------------
// K2K3 fused: hop-2 gather directly in MFMA-fragment layout + GEMM + relu.
// Wave handles 16 queries. Lane (r = lane&15, half = lane>>4).
// Logical-K permutation (same for A and B): afrag[kk] = row elements
// [half*32 + kk*8, +8). Each lane's per-neighbor A-contribution is ONE
// contiguous uint4 (16B) of the 64B fp4 h1 row; the 4 lanes sharing a row
// coalesce to one 64B request. No LDS, no X buffer.
// C/D layout: out col = c0 + (lane&15), out row = q0 + (lane>>4)*4 + reg.
// ---------------------------------------------------------------------------
__global__ __launch_bounds__(256) void hop2_gemm_kernel(
    const int* __restrict__ inputs, const int* __restrict__ nbr,
    const unsigned* __restrict__ h1_4, const float* __restrict__ emb,
    const unsigned short* __restrict__ Wb, const float* __restrict__ bias,
    float* __restrict__ out, int Fdim) {
  int wid = threadIdx.x >> 6;
  int lane = threadIdx.x & 63;
  int r = lane & 15;
  int half = lane >> 4;
  int q0 = (blockIdx.x * 4 + wid) * 16;

  int node = inputs[q0 + r];
  const int4* nb4 = reinterpret_cast<const int4*>(nbr) + (size_t)node * 4;
  int4 na = nb4[0], nbv = nb4[1], nc = nb4[2], nd = nb4[3];
  int idx[16] = {na.x, na.y, na.z, na.w, nbv.x, nbv.y, nbv.z, nbv.w,
                 nc.x, nc.y, nc.z, nc.w, nd.x, nd.y, nd.z, nd.w};

  float acc[4][8];
#pragma unroll
  for (int kk = 0; kk < 4; ++kk)
#pragma unroll
    for (int j = 0; j < 8; ++j) acc[kk][j] = 0.f;

#pragma unroll
  for (int m = 0; m < 16; ++m) {
    uint4 v = *reinterpret_cast<const uint4*>(h1_4 + (size_t)idx[m] * 16 + half * 4);
    float t[8];
    dec_fp4x8(v.x, t);
#pragma unroll
    for (int j = 0; j < 8; ++j) acc[0][j] += t[j];
    dec_fp4x8(v.y, t);
#pragma unroll
    for (int j = 0; j < 8; ++j) acc[1][j] += t[j];
    dec_fp4x8(v.z, t);
#pragma unroll
    for (int j = 0; j < 8; ++j) acc[2][j] += t[j];
    dec_fp4x8(v.w, t);
#pragma unroll
    for (int j = 0; j < 8; ++j) acc[3][j] += t[j];
  }

  // finalize: mean*scale + fp32 self-embedding, pack to bf16 fragments
  bf16x8 afrag[4];
#pragma unroll
  for (int kk = 0; kk < 4; ++kk) {
    const float4* se = reinterpret_cast<const float4*>(
        emb + (size_t)node * EDIM + half * 32 + kk * 8);
    float4 s0 = se[0], s1 = se[1];
    float v0 = acc[kk][0] * H1_S_OVER16 + s0.x;
    float v1 = acc[kk][1] * H1_S_OVER16 + s0.y;
    float v2 = acc[kk][2] * H1_S_OVER16 + s0.z;
    float v3 = acc[kk][3] * H1_S_OVER16 + s0.w;
    float v4 = acc[kk][4] * H1_S_OVER16 + s1.x;
    float v5 = acc[kk][5] * H1_S_OVER16 + s1.y;
    float v6 = acc[kk][6] * H1_S_OVER16 + s1.z;
    float v7 = acc[kk][7] * H1_S_OVER16 + s1.w;
    uint4 o;
    o.x = pack_bf16(v0, v1);
    o.y = pack_bf16(v2, v3);
    o.z = pack_bf16(v4, v5);
    o.w = pack_bf16(v6, v7);
    afrag[kk] = *reinterpret_cast<bf16x8*>(&o);
  }

  // GEMM sweep over output features
  for (int c0 = 0; c0 < Fdim; c0 += 16) {
    f32x4 dacc = {0.f, 0.f, 0.f, 0.f};
#pragma unroll
    for (int kk = 0; kk < 4; ++kk) {
      uint4 w = *reinterpret_cast<const uint4*>(
          Wb + (size_t)(c0 + r) * EDIM + half * 32 + kk * 8);
      bf16x8 bfrag = *reinterpret_cast<bf16x8*>(&w);
      dacc = __builtin_amdgcn_mfma_f32_16x16x32_bf16(afrag[kk], bfrag, dacc, 0, 0, 0);
    }
    float bv = bias[c0 + r];
#pragma unroll
    for (int reg = 0; reg < 4; ++reg) {
      out[(size_t)(q0 + half * 4 + reg) * Fdim + c0 + r] = fmaxf(dacc[reg] + bv, 0.f);
    }
  }
}

// ---------------------------------------------------------------------------
extern "C" void kernel_launch(void* const* d_in, const int* in_sizes, int n_in,
                              void* d_out, int out_size, void* d_ws, size_t ws_size,
                              hipStream_t stream) {
  const int* inputs = (const int*)d_in[0];    // [B]
  const int* nbr = (const int*)d_in[1];       // [N,16]
  const float* emb = (const float*)d_in[2];   // [N,128]
  const float* W = (const float*)d_in[3];     // [F,128]
  const float* bias = (const float*)d_in[4];  // [F]
  float* out = (float*)d_out;

  const int B = in_sizes[0];
  const int N = in_sizes[2] / EDIM;
  const int F = in_sizes[4];

  unsigned* emb4 = (unsigned*)d_ws;                      // [2][N][8 u32] sliced fp4
  unsigned* h1_4 = emb4 + (size_t)N * 16;                // [N][16 u32] row fp4
  unsigned short* Wb = (unsigned short*)(h1_4 + (size_t)N * 16);  // F*128 bf16

  // K0: emb -> 2-way sliced fp4 table, W -> bf16
  int n8_w = F * EDIM / 8;
  convert_kernel<<<2048, 256, 0, stream>>>(emb, emb4, N, W, Wb, n8_w);

  // K1: hop 1, 2-way column-sliced gather; EXACTLY 2048 co-resident blocks
  // (slice pinning holds), grid-stride over nodes, 8 lanes/node/slice.
  hop1_kernel<<<2048, 256, 0, stream>>>(nbr, emb4, h1_4, N);

  // K2K3: fused hop-2 gather (fragment layout) + GEMM + bias + relu
  int blocks = B / 64;  // 4 waves/block, 16 queries/wave
  hop2_gemm_kernel<<<blocks, 256, 0, stream>>>(inputs, nbr, h1_4, emb, Wb, bias,
                                               out, F);
}

// Round 12
// 62.722 us; speedup vs baseline: 1.0300x; 1.0300x over previous
//
#include <hip/hip_runtime.h>
#include <hip/hip_bf16.h>

#define EDIM 128

typedef __attribute__((ext_vector_type(4))) float f32x4;
typedef __attribute__((ext_vector_type(2))) float f32x2;
typedef __attribute__((ext_vector_type(8))) short bf16x8;

// fp4 e2m1 scales. emb table: x -> fp4(x * EMB_INV), decode * (2/3).
// h1 table:  x -> fp4(x * H1_INV),  decode * (1/6).
#define EMB_INV 1.5f
#define EMB_S_OVER16 0.04166667f   // (2/3)/16  (fold hop-1 mean into dequant)
#define H1_INV 6.0f
#define H1_S_OVER16 0.010416667f   // (1/6)/16  (fold hop-2 mean into dequant)

// ---- helpers ---------------------------------------------------------------
__device__ __forceinline__ unsigned pack_bf16(float lo, float hi) {
  __hip_bfloat16 l = __float2bfloat16(lo);
  __hip_bfloat16 h = __float2bfloat16(hi);
  unsigned short lu = *reinterpret_cast<unsigned short*>(&l);
  unsigned short hu = *reinterpret_cast<unsigned short*>(&h);
  return (unsigned)lu | ((unsigned)hu << 16);
}

// encode one float -> fp4 e2m1 nibble (round-to-nearest on the e2m1 grid)
__device__ __forceinline__ unsigned enc_fp4(float x, float inv) {
  unsigned s = (__float_as_uint(x) >> 31) << 3;
  float m = fabsf(x) * inv;
  unsigned idx = (unsigned)(m > 0.25f) + (m > 0.75f) + (m > 1.25f) + (m > 1.75f)
               + (m > 2.5f) + (m > 3.5f) + (m > 5.0f);
  return idx | s;
}

// pack 8 floats (fp32) -> 8 fp4 nibbles in one u32
__device__ __forceinline__ unsigned enc_fp4x8(const float* a, float pre, float inv) {
  unsigned o = 0;
#pragma unroll
  for (int j = 0; j < 8; ++j) o |= enc_fp4(a[j] * pre, inv) << (4 * j);
  return o;
}

// decode 8 fp4 nibbles (u32) -> 8 floats in fp4-grid units, TRUE element order.
// nibble j = element j. Route: nibble -> fp8 e4m3 byte via v_perm LUT
// (fp4 values {0,.5,1,1.5,2,3,4,6} are exact in e4m3), then cvt_pk_f32_fp8.
__device__ __forceinline__ void dec_fp4x8(unsigned u, float* a) {
  const unsigned LUT_LO = 0x3C383000u;
  const unsigned LUT_HI = 0x4C484440u;
  unsigned mE = u & 0x07070707u;
  unsigned mO = (u >> 4) & 0x07070707u;
  unsigned sE = (u & 0x08080808u) << 4;
  unsigned sO = u & 0x80808080u;
  unsigned E = __builtin_amdgcn_perm(LUT_HI, LUT_LO, mE) | sE;  // e0,e2,e4,e6
  unsigned O = __builtin_amdgcn_perm(LUT_HI, LUT_LO, mO) | sO;  // e1,e3,e5,e7
  f32x2 p;
  p = __builtin_amdgcn_cvt_pk_f32_fp8(E, false); a[0] = p.x; a[2] = p.y;
  p = __builtin_amdgcn_cvt_pk_f32_fp8(E, true);  a[4] = p.x; a[6] = p.y;
  p = __builtin_amdgcn_cvt_pk_f32_fp8(O, false); a[1] = p.x; a[3] = p.y;
  p = __builtin_amdgcn_cvt_pk_f32_fp8(O, true);  a[5] = p.x; a[7] = p.y;
}

// ---------------------------------------------------------------------------
// K0: emb fp32 -> fp4 table in 2-way COLUMN-SPLIT layout [2][N][8 u32]
//     (slice s = columns [64s, 64s+64); sub-table = 3.2 MB < 4 MB XCD L2),
//     W fp32 -> bf16 (row-major).
// ---------------------------------------------------------------------------
__global__ __launch_bounds__(256) void convert_kernel(
    const float* __restrict__ emb, unsigned* __restrict__ emb4, int nNodes,
    const float* __restrict__ W, unsigned short* __restrict__ Wb, int n8_w) {
  int n8_emb = nNodes * 16;
  int total = n8_emb + n8_w;
  for (int i = blockIdx.x * 256 + threadIdx.x; i < total; i += gridDim.x * 256) {
    if (i < n8_emb) {
      int n = i >> 4;       // node
      int j = i & 15;       // 8-float group within row
      const float4* s4 = reinterpret_cast<const float4*>(emb) + (size_t)i * 2;
      float4 a = s4[0], b = s4[1];
      unsigned u = enc_fp4(a.x, EMB_INV) | (enc_fp4(a.y, EMB_INV) << 4) |
                   (enc_fp4(a.z, EMB_INV) << 8) | (enc_fp4(a.w, EMB_INV) << 12) |
                   (enc_fp4(b.x, EMB_INV) << 16) | (enc_fp4(b.y, EMB_INV) << 20) |
                   (enc_fp4(b.z, EMB_INV) << 24) | (enc_fp4(b.w, EMB_INV) << 28);
      int s = j >> 3;       // slice (0/1)
      int w = j & 7;        // u32 within slice
      emb4[((size_t)s * nNodes + n) * 8 + w] = u;
    } else {
      int j = i - n8_emb;
      const float4* s4 = reinterpret_cast<const float4*>(W) + (size_t)j * 2;
      float4 a = s4[0], b = s4[1];
      uint4 o;
      o.x = pack_bf16(a.x, a.y);
      o.y = pack_bf16(a.z, a.w);
      o.z = pack_bf16(b.x, b.y);
      o.w = pack_bf16(b.z, b.w);
      *(reinterpret_cast<uint4*>(Wb) + j) = o;
    }
  }
}

// ---------------------------------------------------------------------------
// K1 (run TWICE, pass = 0,1): h1_fp4[n][cols of slice] = mean over 16
// neighbors of sub-table[nbr]. REPLICATION, not partitioning: during one
// pass every XCD's L2 caches the same 3.2 MB sub-table (fits 4 MB) -> all
// gathers are L2 hits after warm-up. No dispatch/pinning assumptions
// (r8-r11 lesson: bid->XCD pinning is unreliable; time-separated passes
// with an L2-sized working set are robust).
// 8 lanes per node: lane owns u32 (tid&7) of the 32B slice row ->
// one coalesced 32B request per neighbor row-slice; acc[8], low VGPR.
// ---------------------------------------------------------------------------
__global__ __launch_bounds__(256) void hop1_kernel(
    const int* __restrict__ nbr, const unsigned* __restrict__ sub,
    unsigned* __restrict__ dst4, int nNodes, int slice) {
  int node = blockIdx.x * 32 + (threadIdx.x >> 3);
  if (node >= nNodes) return;
  int l8 = threadIdx.x & 7;

  const int4* nb4 = reinterpret_cast<const int4*>(nbr) + (size_t)node * 4;
  int4 a = nb4[0], b = nb4[1], c = nb4[2], d = nb4[3];
  int idx[16] = {a.x, a.y, a.z, a.w, b.x, b.y, b.z, b.w,
                 c.x, c.y, c.z, c.w, d.x, d.y, d.z, d.w};

  float acc[8] = {0.f, 0.f, 0.f, 0.f, 0.f, 0.f, 0.f, 0.f};
#pragma unroll
  for (int m = 0; m < 16; ++m) {
    unsigned u = sub[(size_t)idx[m] * 8 + l8];
    float t[8];
    dec_fp4x8(u, t);
#pragma unroll
    for (int j = 0; j < 8; ++j) acc[j] += t[j];
  }
  // h1 row layout [N][16 u32]; this thread owns u32 (slice*8 + l8)
  dst4[(size_t)node * 16 + slice * 8 + l8] = enc_fp4x8(acc, EMB_S_OVER16, H1_INV);
}

// ---------------------------------------------------------------------------
// K2K3 fused: hop-2 gather directly in MFMA-fragment layout + GEMM + relu.
// Wave handles 16 queries. Lane (r = lane&15, half = lane>>4).
// Logical-K permutation (same for A and B): afrag[kk] = row elements
// [half*32 + kk*8, +8). Each lane's per-neighbor A-contribution is ONE
// contiguous uint4 (16B) of the 64B fp4 h1 row; the 4 lanes sharing a row
// coalesce to one 64B request. No LDS, no X buffer.
// C/D layout: out col = c0 + (lane&15), out row = q0 + (lane>>4)*4 + reg.
// ---------------------------------------------------------------------------
__global__ __launch_bounds__(256) void hop2_gemm_kernel(
    const int* __restrict__ inputs, const int* __restrict__ nbr,
    const unsigned* __restrict__ h1_4, const float* __restrict__ emb,
    const unsigned short* __restrict__ Wb, const float* __restrict__ bias,
    float* __restrict__ out, int Fdim) {
  int wid = threadIdx.x >> 6;
  int lane = threadIdx.x & 63;
  int r = lane & 15;
  int half = lane >> 4;
  int q0 = (blockIdx.x * 4 + wid) * 16;

  int node = inputs[q0 + r];
  const int4* nb4 = reinterpret_cast<const int4*>(nbr) + (size_t)node * 4;
  int4 na = nb4[0], nbv = nb4[1], nc = nb4[2], nd = nb4[3];
  int idx[16] = {na.x, na.y, na.z, na.w, nbv.x, nbv.y, nbv.z, nbv.w,
                 nc.x, nc.y, nc.z, nc.w, nd.x, nd.y, nd.z, nd.w};

  float acc[4][8];
#pragma unroll
  for (int kk = 0; kk < 4; ++kk)
#pragma unroll
    for (int j = 0; j < 8; ++j) acc[kk][j] = 0.f;

#pragma unroll
  for (int m = 0; m < 16; ++m) {
    uint4 v = *reinterpret_cast<const uint4*>(h1_4 + (size_t)idx[m] * 16 + half * 4);
    float t[8];
    dec_fp4x8(v.x, t);
#pragma unroll
    for (int j = 0; j < 8; ++j) acc[0][j] += t[j];
    dec_fp4x8(v.y, t);
#pragma unroll
    for (int j = 0; j < 8; ++j) acc[1][j] += t[j];
    dec_fp4x8(v.z, t);
#pragma unroll
    for (int j = 0; j < 8; ++j) acc[2][j] += t[j];
    dec_fp4x8(v.w, t);
#pragma unroll
    for (int j = 0; j < 8; ++j) acc[3][j] += t[j];
  }

  // finalize: mean*scale + fp32 self-embedding, pack to bf16 fragments
  bf16x8 afrag[4];
#pragma unroll
  for (int kk = 0; kk < 4; ++kk) {
    const float4* se = reinterpret_cast<const float4*>(
        emb + (size_t)node * EDIM + half * 32 + kk * 8);
    float4 s0 = se[0], s1 = se[1];
    float v0 = acc[kk][0] * H1_S_OVER16 + s0.x;
    float v1 = acc[kk][1] * H1_S_OVER16 + s0.y;
    float v2 = acc[kk][2] * H1_S_OVER16 + s0.z;
    float v3 = acc[kk][3] * H1_S_OVER16 + s0.w;
    float v4 = acc[kk][4] * H1_S_OVER16 + s1.x;
    float v5 = acc[kk][5] * H1_S_OVER16 + s1.y;
    float v6 = acc[kk][6] * H1_S_OVER16 + s1.z;
    float v7 = acc[kk][7] * H1_S_OVER16 + s1.w;
    uint4 o;
    o.x = pack_bf16(v0, v1);
    o.y = pack_bf16(v2, v3);
    o.z = pack_bf16(v4, v5);
    o.w = pack_bf16(v6, v7);
    afrag[kk] = *reinterpret_cast<bf16x8*>(&o);
  }

  // GEMM sweep over output features
  for (int c0 = 0; c0 < Fdim; c0 += 16) {
    f32x4 dacc = {0.f, 0.f, 0.f, 0.f};
#pragma unroll
    for (int kk = 0; kk < 4; ++kk) {
      uint4 w = *reinterpret_cast<const uint4*>(
          Wb + (size_t)(c0 + r) * EDIM + half * 32 + kk * 8);
      bf16x8 bfrag = *reinterpret_cast<bf16x8*>(&w);
      dacc = __builtin_amdgcn_mfma_f32_16x16x32_bf16(afrag[kk], bfrag, dacc, 0, 0, 0);
    }
    float bv = bias[c0 + r];
#pragma unroll
    for (int reg = 0; reg < 4; ++reg) {
      out[(size_t)(q0 + half * 4 + reg) * Fdim + c0 + r] = fmaxf(dacc[reg] + bv, 0.f);
    }
  }
}

// ---------------------------------------------------------------------------
extern "C" void kernel_launch(void* const* d_in, const int* in_sizes, int n_in,
                              void* d_out, int out_size, void* d_ws, size_t ws_size,
                              hipStream_t stream) {
  const int* inputs = (const int*)d_in[0];    // [B]
  const int* nbr = (const int*)d_in[1];       // [N,16]
  const float* emb = (const float*)d_in[2];   // [N,128]
  const float* W = (const float*)d_in[3];     // [F,128]
  const float* bias = (const float*)d_in[4];  // [F]
  float* out = (float*)d_out;

  const int B = in_sizes[0];
  const int N = in_sizes[2] / EDIM;
  const int F = in_sizes[4];

  unsigned* emb4 = (unsigned*)d_ws;                      // [2][N][8 u32] split fp4
  unsigned* h1_4 = emb4 + (size_t)N * 16;                // [N][16 u32] row fp4
  unsigned short* Wb = (unsigned short*)(h1_4 + (size_t)N * 16);  // F*128 bf16

  // K0: emb -> 2-way column-split fp4 table, W -> bf16
  int n8_w = F * EDIM / 8;
  convert_kernel<<<4096, 256, 0, stream>>>(emb, emb4, N, W, Wb, n8_w);

  // K1: hop 1 as TWO time-separated passes; each pass's 3.2 MB sub-table is
  // replicated into every XCD's L2 (no pinning assumptions).
  int blocks1 = (N + 31) / 32;
  hop1_kernel<<<blocks1, 256, 0, stream>>>(nbr, emb4, h1_4, N, 0);
  hop1_kernel<<<blocks1, 256, 0, stream>>>(nbr, emb4 + (size_t)N * 8, h1_4, N, 1);

  // K2K3: fused hop-2 gather (fragment layout) + GEMM + bias + relu
  int blocks = B / 64;  // 4 waves/block, 16 queries/wave
  hop2_gemm_kernel<<<blocks, 256, 0, stream>>>(inputs, nbr, h1_4, emb, Wb, bias,
                                               out, F);
}

// Round 13
// 56.944 us; speedup vs baseline: 1.1345x; 1.1015x over previous
//
#include <hip/hip_runtime.h>
#include <hip/hip_bf16.h>

#define EDIM 128

typedef __attribute__((ext_vector_type(4))) float f32x4;
typedef __attribute__((ext_vector_type(2))) float f32x2;
typedef __attribute__((ext_vector_type(8))) short bf16x8;

// fp4 e2m1 scales. emb table: x -> fp4(x * EMB_INV), decode * (2/3).
// h1 table:  x -> fp4(x * H1_INV),  decode * (1/6).
#define EMB_INV 1.5f
#define EMB_S_OVER16 0.04166667f   // (2/3)/16  (fold hop-1 mean into dequant)
#define H1_INV 6.0f
#define H1_S_OVER16 0.010416667f   // (1/6)/16  (fold hop-2 mean into dequant)

// ---- helpers ---------------------------------------------------------------
__device__ __forceinline__ unsigned pack_bf16(float lo, float hi) {
  __hip_bfloat16 l = __float2bfloat16(lo);
  __hip_bfloat16 h = __float2bfloat16(hi);
  unsigned short lu = *reinterpret_cast<unsigned short*>(&l);
  unsigned short hu = *reinterpret_cast<unsigned short*>(&h);
  return (unsigned)lu | ((unsigned)hu << 16);
}

// encode one float -> fp4 e2m1 nibble (round-to-nearest on the e2m1 grid)
__device__ __forceinline__ unsigned enc_fp4(float x, float inv) {
  unsigned s = (__float_as_uint(x) >> 31) << 3;
  float m = fabsf(x) * inv;
  unsigned idx = (unsigned)(m > 0.25f) + (m > 0.75f) + (m > 1.25f) + (m > 1.75f)
               + (m > 2.5f) + (m > 3.5f) + (m > 5.0f);
  return idx | s;
}

// pack 8 floats (fp32) -> 8 fp4 nibbles in one u32
__device__ __forceinline__ unsigned enc_fp4x8(const float* a, float pre, float inv) {
  unsigned o = 0;
#pragma unroll
  for (int j = 0; j < 8; ++j) o |= enc_fp4(a[j] * pre, inv) << (4 * j);
  return o;
}

// decode 8 fp4 nibbles (u32) -> 8 floats in fp4-grid units, TRUE element order.
// nibble j = element j. Route: nibble -> fp8 e4m3 byte via v_perm LUT
// (fp4 values {0,.5,1,1.5,2,3,4,6} are exact in e4m3), then cvt_pk_f32_fp8.
__device__ __forceinline__ void dec_fp4x8(unsigned u, float* a) {
  const unsigned LUT_LO = 0x3C383000u;
  const unsigned LUT_HI = 0x4C484440u;
  unsigned mE = u & 0x07070707u;
  unsigned mO = (u >> 4) & 0x07070707u;
  unsigned sE = (u & 0x08080808u) << 4;
  unsigned sO = u & 0x80808080u;
  unsigned E = __builtin_amdgcn_perm(LUT_HI, LUT_LO, mE) | sE;  // e0,e2,e4,e6
  unsigned O = __builtin_amdgcn_perm(LUT_HI, LUT_LO, mO) | sO;  // e1,e3,e5,e7
  f32x2 p;
  p = __builtin_amdgcn_cvt_pk_f32_fp8(E, false); a[0] = p.x; a[2] = p.y;
  p = __builtin_amdgcn_cvt_pk_f32_fp8(E, true);  a[4] = p.x; a[6] = p.y;
  p = __builtin_amdgcn_cvt_pk_f32_fp8(O, false); a[1] = p.x; a[3] = p.y;
  p = __builtin_amdgcn_cvt_pk_f32_fp8(O, true);  a[5] = p.x; a[7] = p.y;
}

// ---------------------------------------------------------------------------
// K0: emb fp32 -> fp4 table [N][16 u32] (row = 64B), W fp32 -> bf16.
// (r7 layout — plain, unsliced; all partitioning schemes lost to it.)
// ---------------------------------------------------------------------------
__global__ __launch_bounds__(256) void convert_kernel(
    const float* __restrict__ emb, unsigned* __restrict__ emb4, int n8_emb,
    const float* __restrict__ W, unsigned short* __restrict__ Wb, int n8_w) {
  int total = n8_emb + n8_w;
  for (int i = blockIdx.x * 256 + threadIdx.x; i < total; i += gridDim.x * 256) {
    if (i < n8_emb) {
      const float4* s4 = reinterpret_cast<const float4*>(emb) + (size_t)i * 2;
      float4 a = s4[0], b = s4[1];
      unsigned u = enc_fp4(a.x, EMB_INV) | (enc_fp4(a.y, EMB_INV) << 4) |
                   (enc_fp4(a.z, EMB_INV) << 8) | (enc_fp4(a.w, EMB_INV) << 12) |
                   (enc_fp4(b.x, EMB_INV) << 16) | (enc_fp4(b.y, EMB_INV) << 20) |
                   (enc_fp4(b.z, EMB_INV) << 24) | (enc_fp4(b.w, EMB_INV) << 28);
      emb4[i] = u;
    } else {
      int j = i - n8_emb;
      const float4* s4 = reinterpret_cast<const float4*>(W) + (size_t)j * 2;
      float4 a = s4[0], b = s4[1];
      uint4 o;
      o.x = pack_bf16(a.x, a.y);
      o.y = pack_bf16(a.z, a.w);
      o.z = pack_bf16(b.x, b.y);
      o.w = pack_bf16(b.z, b.w);
      *(reinterpret_cast<uint4*>(Wb) + j) = o;
    }
  }
}

// ---------------------------------------------------------------------------
// K1: h1_fp4[n] = mean over 16 neighbors of emb_fp4[nbr]  (r7 version — at
// the measured random-line roofline: ~77MB L2-miss lines @ ~3.6 TB/s).
// 16 lanes/node, 1 u32 (8 fp4) per lane per neighbor row (64B rows).
// fp32 accumulate, fp4 output. h1 store is NONTEMPORAL (streaming output;
// don't evict the emb4 gather table from L2).
// ---------------------------------------------------------------------------
__global__ __launch_bounds__(256) void hop1_kernel(
    const int* __restrict__ nbr, const unsigned* __restrict__ src4,
    unsigned* __restrict__ dst4, int nNodes) {
  int node = blockIdx.x * 16 + (threadIdx.x >> 4);
  if (node >= nNodes) return;
  int lane = threadIdx.x & 15;

  const int4* nb4 = reinterpret_cast<const int4*>(nbr) + (size_t)node * 4;
  int4 a = nb4[0], b = nb4[1], c = nb4[2], d = nb4[3];
  int idx[16] = {a.x, a.y, a.z, a.w, b.x, b.y, b.z, b.w,
                 c.x, c.y, c.z, c.w, d.x, d.y, d.z, d.w};

  float acc[8] = {0.f, 0.f, 0.f, 0.f, 0.f, 0.f, 0.f, 0.f};
#pragma unroll
  for (int m = 0; m < 16; ++m) {
    unsigned u = src4[(size_t)idx[m] * 16 + lane];
    float t[8];
    dec_fp4x8(u, t);
#pragma unroll
    for (int j = 0; j < 8; ++j) acc[j] += t[j];
  }
  __builtin_nontemporal_store(enc_fp4x8(acc, EMB_S_OVER16, H1_INV),
                              dst4 + (size_t)node * 16 + lane);
}

// ---------------------------------------------------------------------------
// K2K3 fused, 4-way m-split: block = 4 waves serving the SAME 16 queries.
// Wave w decodes neighbors m in [4w, 4w+4) only; fp32 partial fragments are
// reduced through LDS [e=32][w=4][lane=64] (bank = lane%32 on every access ->
// conflict-free); then wave w sweeps output features c0 = w*16 step 64.
// Result: 4096 waves (16/CU, 4/SIMD) vs the old 1024 (1/SIMD) -> gather
// latency actually hidden. No dispatch/XCD assumptions (same-block = same CU).
// Fragment layout identical to r7 (logical-K permutation shared by A and B).
// C/D: out col = c0 + (lane&15), out row = q0 + (lane>>4)*4 + reg.
// ---------------------------------------------------------------------------
__global__ __launch_bounds__(256) void hop2_gemm_kernel(
    const int* __restrict__ inputs, const int* __restrict__ nbr,
    const unsigned* __restrict__ h1_4, const float* __restrict__ emb,
    const unsigned short* __restrict__ Wb, const float* __restrict__ bias,
    float* __restrict__ out, int Fdim) {
  __shared__ float lds[32][4][64];  // [elem][wave][lane] = 32 KB
  int w = threadIdx.x >> 6;
  int lane = threadIdx.x & 63;
  int r = lane & 15;
  int half = lane >> 4;
  int q0 = blockIdx.x * 16;

  int node = inputs[q0 + r];
  // this wave's 4 neighbor ids (int4 #w of the 16-int row)
  int4 nn = *(reinterpret_cast<const int4*>(nbr) + (size_t)node * 4 + w);
  int idx[4] = {nn.x, nn.y, nn.z, nn.w};

  float acc[4][8];
#pragma unroll
  for (int kk = 0; kk < 4; ++kk)
#pragma unroll
    for (int j = 0; j < 8; ++j) acc[kk][j] = 0.f;

#pragma unroll
  for (int m = 0; m < 4; ++m) {
    uint4 v = *reinterpret_cast<const uint4*>(h1_4 + (size_t)idx[m] * 16 + half * 4);
    float t[8];
    dec_fp4x8(v.x, t);
#pragma unroll
    for (int j = 0; j < 8; ++j) acc[0][j] += t[j];
    dec_fp4x8(v.y, t);
#pragma unroll
    for (int j = 0; j < 8; ++j) acc[1][j] += t[j];
    dec_fp4x8(v.z, t);
#pragma unroll
    for (int j = 0; j < 8; ++j) acc[2][j] += t[j];
    dec_fp4x8(v.w, t);
#pragma unroll
    for (int j = 0; j < 8; ++j) acc[3][j] += t[j];
  }

  // stage partials: lds[kk*8+j][w][lane]  (bank = lane%32, conflict-free)
#pragma unroll
  for (int kk = 0; kk < 4; ++kk)
#pragma unroll
    for (int j = 0; j < 8; ++j) lds[kk * 8 + j][w][lane] = acc[kk][j];
  __syncthreads();

  // reduce across the 4 waves + finalize + pack bf16 fragments
  bf16x8 afrag[4];
#pragma unroll
  for (int kk = 0; kk < 4; ++kk) {
    float tot[8];
#pragma unroll
    for (int j = 0; j < 8; ++j) {
      int e = kk * 8 + j;
      tot[j] = (lds[e][0][lane] + lds[e][1][lane]) +
               (lds[e][2][lane] + lds[e][3][lane]);
    }
    const float4* se = reinterpret_cast<const float4*>(
        emb + (size_t)node * EDIM + half * 32 + kk * 8);
    float4 s0 = se[0], s1 = se[1];
    uint4 o;
    o.x = pack_bf16(tot[0] * H1_S_OVER16 + s0.x, tot[1] * H1_S_OVER16 + s0.y);
    o.y = pack_bf16(tot[2] * H1_S_OVER16 + s0.z, tot[3] * H1_S_OVER16 + s0.w);
    o.z = pack_bf16(tot[4] * H1_S_OVER16 + s1.x, tot[5] * H1_S_OVER16 + s1.y);
    o.w = pack_bf16(tot[6] * H1_S_OVER16 + s1.z, tot[7] * H1_S_OVER16 + s1.w);
    afrag[kk] = *reinterpret_cast<bf16x8*>(&o);
  }

  // GEMM sweep: wave w owns feature columns c0 = w*16, step 64
  for (int c0 = w * 16; c0 < Fdim; c0 += 64) {
    f32x4 dacc = {0.f, 0.f, 0.f, 0.f};
#pragma unroll
    for (int kk = 0; kk < 4; ++kk) {
      uint4 wv = *reinterpret_cast<const uint4*>(
          Wb + (size_t)(c0 + r) * EDIM + half * 32 + kk * 8);
      bf16x8 bfrag = *reinterpret_cast<bf16x8*>(&wv);
      dacc = __builtin_amdgcn_mfma_f32_16x16x32_bf16(afrag[kk], bfrag, dacc, 0, 0, 0);
    }
    float bv = bias[c0 + r];
#pragma unroll
    for (int reg = 0; reg < 4; ++reg) {
      __builtin_nontemporal_store(
          fmaxf(dacc[reg] + bv, 0.f),
          out + (size_t)(q0 + half * 4 + reg) * Fdim + c0 + r);
    }
  }
}

// ---------------------------------------------------------------------------
extern "C" void kernel_launch(void* const* d_in, const int* in_sizes, int n_in,
                              void* d_out, int out_size, void* d_ws, size_t ws_size,
                              hipStream_t stream) {
  const int* inputs = (const int*)d_in[0];    // [B]
  const int* nbr = (const int*)d_in[1];       // [N,16]
  const float* emb = (const float*)d_in[2];   // [N,128]
  const float* W = (const float*)d_in[3];     // [F,128]
  const float* bias = (const float*)d_in[4];  // [F]
  float* out = (float*)d_out;

  const int B = in_sizes[0];
  const int N = in_sizes[2] / EDIM;
  const int F = in_sizes[4];

  unsigned* emb4 = (unsigned*)d_ws;                      // [N][16 u32] fp4
  unsigned* h1_4 = emb4 + (size_t)N * 16;                // [N][16 u32] fp4
  unsigned short* Wb = (unsigned short*)(h1_4 + (size_t)N * 16);  // F*128 bf16

  // K0: emb -> fp4 table, W -> bf16
  int n8_emb = N * EDIM / 8;
  int n8_w = F * EDIM / 8;
  convert_kernel<<<4096, 256, 0, stream>>>(emb, emb4, n8_emb, W, Wb, n8_w);

  // K1: hop 1 over all nodes (fp4 gather, fp4 output, NT h1 store)
  hop1_kernel<<<(N + 15) / 16, 256, 0, stream>>>(nbr, emb4, h1_4, N);

  // K2K3: fused hop-2 (4-way m-split, LDS reduce) + GEMM + bias + relu
  hop2_gemm_kernel<<<B / 16, 256, 0, stream>>>(inputs, nbr, h1_4, emb, Wb, bias,
                                               out, F);
}